// Round 1
// baseline (1297.227 us; speedup 1.0000x reference)
//
#include <hip/hip_runtime.h>
#include <limits.h>
#include <math.h>

// CalcImpute: per-row top-16-smallest (stable, lower-index-on-tie) over 50000
// donors, then masked mean of gathered donor values.
// Memory-bound: 1.64 GB of dist matrix streamed once from HBM.

#define K    16
#define NDON 50000
#define NF4  (NDON / 4)   // 12500 float4 per row

__device__ __forceinline__ bool lexless(float v1, int i1, float v2, int i2) {
    // strict lexicographic (value, index) less-than; matches XLA top_k
    // stability (equal values -> lower index first).
    return (v1 < v2) || ((v1 == v2) && (i1 < i2));
}

__global__ void __launch_bounds__(256, 4)
calc_impute_topk(const float* __restrict__ dist,
                 const float* __restrict__ fitX,
                 const int*   __restrict__ mask,
                 float* __restrict__ out,
                 int nrows)
{
    const int gtid = blockIdx.x * blockDim.x + threadIdx.x;
    const int wrow = gtid >> 6;          // one wave per row
    const int lane = threadIdx.x & 63;
    if (wrow >= nrows) return;

    const float* __restrict__ row = dist + (size_t)wrow * NDON;

    // Per-lane sorted ascending (lex) top-16 candidate list, all accesses
    // compile-time indexed (stays in VGPRs).
    float vals[K];
    int   idxs[K];
#pragma unroll
    for (int j = 0; j < K; ++j) { vals[j] = INFINITY; idxs[j] = INT_MAX; }

    // Wave-shared (stale) upper bound on the global 16th-smallest value.
    float Tv = INFINITY;

    const int steps = (NF4 + 63) >> 6;   // 196
    for (int s = 0; s < steps; ++s) {
        const int f4 = (s << 6) + lane;
        float4 d;
        if (f4 < NF4) {
            d = reinterpret_cast<const float4*>(row)[f4];
        } else {
            d.x = d.y = d.z = d.w = INFINITY;  // fails the gate
        }
        const int base = f4 << 2;
#pragma unroll
        for (int e = 0; e < 4; ++e) {
            float v = (e == 0) ? d.x : (e == 1) ? d.y : (e == 2) ? d.z : d.w;
            if (v != v) v = 1e10f;             // nan_to_num(nan=1e10)
            const int i = base + e;
            // Loose global gate (value-only, stale T is an upper bound of the
            // final 16th-smallest -> never rejects a true top-16 element),
            // exact local gate (lex vs this lane's current 16th).
            if ((v <= Tv) && lexless(v, i, vals[K - 1], idxs[K - 1])) {
                vals[K - 1] = v; idxs[K - 1] = i;
#pragma unroll
                for (int j = K - 1; j > 0; --j) {
                    const bool sw = lexless(vals[j], idxs[j], vals[j - 1], idxs[j - 1]);
                    const float tv = vals[j];     const int ti = idxs[j];
                    const float pv = vals[j - 1]; const int pi = idxs[j - 1];
                    vals[j]     = sw ? pv : tv;   idxs[j]     = sw ? pi : ti;
                    vals[j - 1] = sw ? tv : pv;   idxs[j - 1] = sw ? ti : pi;
                }
            }
        }
        // Refresh the shared threshold: wave-min of per-lane 16th-smallest.
        // Every step for the first 8 (lists filling up), then every 8th.
        if (s < 8 || (s & 7) == 7) {
            float tv = vals[K - 1];
#pragma unroll
            for (int m = 32; m >= 1; m >>= 1) {
                const float ov = __shfl_xor(tv, m, 64);
                tv = (ov < tv) ? ov : tv;
            }
            Tv = tv;
        }
    }

    // Merge the 64 per-lane sorted lists: 16 rounds of pop-global-lexmin.
    float s_w = 0.0f, s_wx = 0.0f;
#pragma unroll 1
    for (int r = 0; r < K; ++r) {
        float mv = vals[0]; int mi = idxs[0];
#pragma unroll
        for (int m = 32; m >= 1; m >>= 1) {
            const float ov = __shfl_xor(mv, m, 64);
            const int   oi = __shfl_xor(mi, m, 64);
            if (lexless(ov, oi, mv, mi)) { mv = ov; mi = oi; }
        }
        // Unique winner (indices are unique); it pops its head.
        if (vals[0] == mv && idxs[0] == mi) {
#pragma unroll
            for (int j = 0; j < K - 1; ++j) { vals[j] = vals[j + 1]; idxs[j] = idxs[j + 1]; }
            vals[K - 1] = INFINITY; idxs[K - 1] = INT_MAX;
        }
        // All lanes accumulate uniformly (same-address loads broadcast).
        const float w = (float)(1 - mask[mi]);
        s_w  += w;
        s_wx += w * fitX[mi];
    }

    if (lane == 0) {
        out[wrow] = s_wx / ((s_w == 0.0f) ? 1.0f : s_w);
    }
}

extern "C" void kernel_launch(void* const* d_in, const int* in_sizes, int n_in,
                              void* d_out, int out_size, void* d_ws, size_t ws_size,
                              hipStream_t stream) {
    const float* dist = (const float*)d_in[0];
    // d_in[1] is n_neighbors (==16, fixed by the problem; K hardcoded)
    const float* fitX = (const float*)d_in[2];
    const int*   mask = (const int*)d_in[3];
    float* out = (float*)d_out;

    const int nrows = out_size;                 // 8192
    const int threads = 256;                    // 4 waves/block, 1 row/wave
    const int blocks = (nrows * 64 + threads - 1) / threads;

    calc_impute_topk<<<blocks, threads, 0, stream>>>(dist, fitX, mask, out, nrows);
}

// Round 2
// 387.250 us; speedup vs baseline: 3.3498x; 3.3498x over previous
//
#include <hip/hip_runtime.h>
#include <limits.h>
#include <math.h>

// CalcImpute: per-row top-16-smallest (stable: lexicographic (value,index))
// over 50000 donors, then masked mean of gathered donor values.
// Strategy: wave-global top-16 list REPLICATED in every lane's registers.
// Hot path = compare 8 streamed elements against the exact running 16th
// smallest (Tv); candidates are rare (~84/row) and inserted wave-uniformly
// via ballot + shfl broadcast. Memory-bound target: 1.64 GB streamed once.

#define K          16
#define NDON       50000
#define NF4        12500      // float4 per row
#define MAIN_START 64         // prologue consumes f4 [0, 64)
#define FULL_STEPS 97         // 97 steps x 128 f4 (2/lane) covers [64, 12480)
#define TAIL_START 12480      // remaining 20 f4

__device__ __forceinline__ bool lexless(float v1, int i1, float v2, int i2) {
    return (v1 < v2) || ((v1 == v2) && (i1 < i2));
}

__device__ __forceinline__ float nanfix(float v) { return (v != v) ? 1e10f : v; }

// Insert candidate (cv,ci) into the sorted (ascending lex) replicated list.
// Called with wave-uniform (cv,ci); all control flow here is wave-uniform.
__device__ __forceinline__ void insert16(float (&vals)[K], int (&idxs)[K],
                                         float cv, int ci) {
    if (!lexless(cv, ci, vals[K - 1], idxs[K - 1])) return;
    bool prev = true;  // cand < vals[15] (guard above)
#pragma unroll
    for (int j = K - 1; j >= 1; --j) {
        const bool up = lexless(cv, ci, vals[j - 1], idxs[j - 1]);
        const float nv = up ? vals[j - 1] : (prev ? cv : vals[j]);
        const int   ni = up ? idxs[j - 1] : (prev ? ci : idxs[j]);
        vals[j] = nv; idxs[j] = ni;
        prev = up;
    }
    if (prev) { vals[0] = cv; idxs[0] = ci; }
}

// compare-exchange for the prologue 4-sort
#define CE(va, ia, vb, ib)                                         \
    {                                                              \
        const bool sw_ = lexless(vb, ib, va, ia);                  \
        const float tv_ = va; const int ti_ = ia;                  \
        va = sw_ ? vb : va; ia = sw_ ? ib : ia;                    \
        vb = sw_ ? tv_ : vb; ib = sw_ ? ti_ : ib;                  \
    }

__global__ void __launch_bounds__(256, 4)
calc_impute_topk(const float* __restrict__ dist,
                 const float* __restrict__ fitX,
                 const int*   __restrict__ mask,
                 float* __restrict__ out,
                 int nrows)
{
    const int gtid = blockIdx.x * blockDim.x + threadIdx.x;
    const int wrow = gtid >> 6;          // one wave per row
    const int lane = threadIdx.x & 63;
    if (wrow >= nrows) return;

    const float4* __restrict__ r4 =
        reinterpret_cast<const float4*>(dist + (size_t)wrow * NDON);

    // ---- Prologue: exact top-16 of the first 256 elements ----
    float4 d = r4[lane];
    float l0 = nanfix(d.x), l1 = nanfix(d.y), l2 = nanfix(d.z), l3 = nanfix(d.w);
    int   j0 = lane * 4, j1 = j0 + 1, j2 = j0 + 2, j3 = j0 + 3;
    // sort the lane's 4 pairs ascending (network: 5 CEs)
    CE(l0, j0, l1, j1); CE(l2, j2, l3, j3);
    CE(l0, j0, l2, j2); CE(l1, j1, l3, j3);
    CE(l1, j1, l2, j2);

    float vals[K];
    int   idxs[K];
#pragma unroll
    for (int r = 0; r < K; ++r) {
        float mv = l0; int mi = j0;
#pragma unroll
        for (int m = 32; m >= 1; m >>= 1) {
            const float ov = __shfl_xor(mv, m, 64);
            const int   oi = __shfl_xor(mi, m, 64);
            if (lexless(ov, oi, mv, mi)) { mv = ov; mi = oi; }
        }
        vals[r] = mv; idxs[r] = mi;          // wave-uniform
        if (l0 == mv && j0 == mi) {          // unique winner pops its head
            l0 = l1; j0 = j1; l1 = l2; j1 = j2; l2 = l3; j2 = j3;
            l3 = INFINITY; j3 = INT_MAX;
        }
    }
    float Tv = vals[K - 1];                  // exact running 16th smallest

#define PROC(ve, ie)                                                   \
    {                                                                  \
        unsigned long long bb_ = __ballot((ve) <= Tv);                 \
        while (bb_) {                                                  \
            const int src_ = __builtin_ctzll(bb_); bb_ &= bb_ - 1;     \
            const float cv_ = __shfl((ve), src_, 64);                  \
            const int   ci_ = __shfl((ie), src_, 64);                  \
            insert16(vals, idxs, cv_, ci_);                            \
        }                                                              \
    }

    // ---- Main loop: 2 float4 per lane per step, prefetch depth 1 ----
    float4 c0 = r4[MAIN_START + lane];
    float4 c1 = r4[MAIN_START + 64 + lane];
    for (int s = 0; s < FULL_STEPS; ++s) {
        float4 n0, n1;
        const bool more = (s + 1 < FULL_STEPS);
        if (more) {
            n0 = r4[MAIN_START + (s + 1) * 128 + lane];
            n1 = r4[MAIN_START + (s + 1) * 128 + 64 + lane];
        }
        const float x0 = nanfix(c0.x), x1 = nanfix(c0.y),
                    x2 = nanfix(c0.z), x3 = nanfix(c0.w);
        const float x4 = nanfix(c1.x), x5 = nanfix(c1.y),
                    x6 = nanfix(c1.z), x7 = nanfix(c1.w);
        const bool any = (x0 <= Tv) || (x1 <= Tv) || (x2 <= Tv) || (x3 <= Tv) ||
                         (x4 <= Tv) || (x5 <= Tv) || (x6 <= Tv) || (x7 <= Tv);
        if (__any(any)) {
            const int b0 = (MAIN_START + s * 128 + lane) * 4;
            PROC(x0, b0 + 0); PROC(x1, b0 + 1);
            PROC(x2, b0 + 2); PROC(x3, b0 + 3);
            PROC(x4, b0 + 256); PROC(x5, b0 + 257);
            PROC(x6, b0 + 258); PROC(x7, b0 + 259);
            Tv = vals[K - 1];
        }
        if (more) { c0 = n0; c1 = n1; }
    }

    // ---- Tail: 20 remaining float4 ----
    {
        float4 e;
        if (lane < (NF4 - TAIL_START)) {
            e = r4[TAIL_START + lane];
        } else {
            e.x = e.y = e.z = e.w = INFINITY;
        }
        const float x0 = nanfix(e.x), x1 = nanfix(e.y),
                    x2 = nanfix(e.z), x3 = nanfix(e.w);
        const int b0 = (TAIL_START + lane) * 4;
        PROC(x0, b0 + 0); PROC(x1, b0 + 1);
        PROC(x2, b0 + 2); PROC(x3, b0 + 3);
    }
#undef PROC

    // ---- Epilogue: list is the sorted global top-16, replicated ----
    float s_w = 0.0f, s_wx = 0.0f;
#pragma unroll
    for (int r = 0; r < K; ++r) {
        const int mi = idxs[r];                       // wave-uniform
        const float w = 1.0f - (float)mask[mi];
        s_w  += w;
        s_wx += w * fitX[mi];
    }
    if (lane == 0) {
        out[wrow] = s_wx / ((s_w == 0.0f) ? 1.0f : s_w);
    }
}

extern "C" void kernel_launch(void* const* d_in, const int* in_sizes, int n_in,
                              void* d_out, int out_size, void* d_ws, size_t ws_size,
                              hipStream_t stream) {
    const float* dist = (const float*)d_in[0];
    // d_in[1] is n_neighbors (==16, fixed; K hardcoded)
    const float* fitX = (const float*)d_in[2];
    const int*   mask = (const int*)d_in[3];
    float* out = (float*)d_out;

    const int nrows = out_size;                 // 8192
    const int threads = 256;                    // 4 waves/block, 1 row/wave
    const int blocks = (nrows * 64 + threads - 1) / threads;

    calc_impute_topk<<<blocks, threads, 0, stream>>>(dist, fitX, mask, out, nrows);
}